// Round 12
// baseline (218.444 us; speedup 1.0000x reference)
//
#include <hip/hip_runtime.h>
#include <hip/hip_bf16.h>

// Problem constants
#define NN     8192      // nodes
#define D0     512       // x feature dim
#define D1     256       // hidden dim (W1 out)
#define D2     64        // z dim (W2 out)
#define NE     262144    // edges

typedef __attribute__((ext_vector_type(8)))  __bf16 bf16x8;
typedef __attribute__((ext_vector_type(16))) float  f32x16;

// ---------------------------------------------------------------------------
// prep_k: fused zero(cnt,cur) + convw1t (W1 -> W1T bf16 hi/lo)
// grid = 16 + 128 blocks
// ---------------------------------------------------------------------------
__global__ __launch_bounds__(256) void prep_k(const float* __restrict__ W,
                                              int4* __restrict__ zero_region,
                                              __bf16* __restrict__ Th,
                                              __bf16* __restrict__ Tl) {
    const int bid = blockIdx.x;
    const int tid = threadIdx.x;
    if (bid < 16) {
        zero_region[bid * 256 + tid] = make_int4(0, 0, 0, 0);
    } else {
        __shared__ float t[32][33];
        const int cid = bid - 16;
        const int c0 = (cid & 7) * 32;      // D1/32 = 8
        const int k0 = (cid >> 3) * 32;     // D0/32 = 16
        {
            int tr  = tid >> 3;
            int tc4 = tid & 7;
            float4 v = *reinterpret_cast<const float4*>(&W[(k0 + tr) * D1 + c0 + tc4 * 4]);
            t[tr][tc4 * 4 + 0] = v.x;
            t[tr][tc4 * 4 + 1] = v.y;
            t[tr][tc4 * 4 + 2] = v.z;
            t[tr][tc4 * 4 + 3] = v.w;
        }
        __syncthreads();
        int c  = tid >> 3;
        int kq = (tid & 7) * 4;
        __bf16 hv[4], lv[4];
        #pragma unroll
        for (int j = 0; j < 4; ++j) {
            float f = t[kq + j][c];
            hv[j] = (__bf16)f;
            lv[j] = (__bf16)(f - (float)hv[j]);
        }
        *reinterpret_cast<uint2*>(&Th[(size_t)(c0 + c) * D0 + k0 + kq]) = *reinterpret_cast<uint2*>(hv);
        *reinterpret_cast<uint2*>(&Tl[(size_t)(c0 + c) * D0 + k0 + kq]) = *reinterpret_cast<uint2*>(lv);
    }
}

// ---------------------------------------------------------------------------
// GEMM1 + hist fused.
// blocks [0,512): gemm1 64x64 tiles (4 waves 2x2, wave=32x32) — 512 blocks
//   load-balance across 256 CUs (128x128 left half the machine idle).
// blocks [512,768): edge_dst histogram.
// ---------------------------------------------------------------------------
__global__ __launch_bounds__(256) void gemm1hist_k(const float* __restrict__ X,
                                                   const __bf16* __restrict__ Wh,
                                                   const __bf16* __restrict__ Wl,
                                                   float* __restrict__ O,
                                                   const int4* __restrict__ dst4,
                                                   int* __restrict__ counts) {
    const int gid = blockIdx.x;
    const int tid = threadIdx.x;
    if (gid >= 512) {
        int i = (gid - 512) * 256 + tid;
        int4 d = dst4[i];
        atomicAdd(&counts[d.x], 1);
        atomicAdd(&counts[d.y], 1);
        atomicAdd(&counts[d.z], 1);
        atomicAdd(&counts[d.w], 1);
        return;
    }
    const int bx = gid >> 2;          // 0..127 row-block
    const int by = gid & 3;           // 0..3   col-block
    const int lane = tid & 63;
    const int w    = tid >> 6;
    const int wm   = w >> 1;
    const int wn   = w & 1;
    const int r32  = lane & 31;
    const int kh   = lane >> 5;
    const int row  = bx * 64 + wm * 32 + r32;
    const int col  = by * 64 + wn * 32 + r32;

    const float*  pX  = X  + (size_t)row * D0;
    const __bf16* pBh = Wh + (size_t)col * D0;
    const __bf16* pBl = Wl + (size_t)col * D0;

    f32x16 acc = {};
    #pragma unroll 4
    for (int k0 = 0; k0 < D0; k0 += 16) {
        const int koff = k0 + kh * 8;
        float4 f0 = *reinterpret_cast<const float4*>(pX + koff);
        float4 f1 = *reinterpret_cast<const float4*>(pX + koff + 4);
        float f[8] = {f0.x, f0.y, f0.z, f0.w, f1.x, f1.y, f1.z, f1.w};
        bf16x8 ah, al;
        #pragma unroll
        for (int e = 0; e < 8; ++e) {
            __bf16 hj = (__bf16)f[e];
            ah[e] = hj;
            al[e] = (__bf16)(f[e] - (float)hj);
        }
        bf16x8 bh = *reinterpret_cast<const bf16x8*>(pBh + koff);
        bf16x8 bl = *reinterpret_cast<const bf16x8*>(pBl + koff);
        acc = __builtin_amdgcn_mfma_f32_32x32x16_bf16(ah, bh, acc, 0, 0, 0);
        acc = __builtin_amdgcn_mfma_f32_32x32x16_bf16(ah, bl, acc, 0, 0, 0);
        acc = __builtin_amdgcn_mfma_f32_32x32x16_bf16(al, bh, acc, 0, 0, 0);
    }

    const int rowBase = bx * 64 + wm * 32;
    const int colBase = by * 64 + wn * 32;
    #pragma unroll
    for (int reg = 0; reg < 16; ++reg) {
        int r = (reg & 3) + 8 * (reg >> 2) + 4 * kh;
        O[(size_t)(rowBase + r) * D1 + colBase + r32] = acc[reg];
    }
}

// shuffle-based scan: 256 threads x 32 counts each
__global__ __launch_bounds__(256) void scan_k(const int* __restrict__ counts,
                                              int* __restrict__ rs) {
    __shared__ int wsum[4];
    const int tid  = threadIdx.x;
    const int base = tid * 32;
    int v[32];
    int s = 0;
    #pragma unroll
    for (int j = 0; j < 8; ++j) {
        int4 q = reinterpret_cast<const int4*>(&counts[base])[j];
        v[j * 4 + 0] = q.x; v[j * 4 + 1] = q.y; v[j * 4 + 2] = q.z; v[j * 4 + 3] = q.w;
        s += q.x + q.y + q.z + q.w;
    }
    int inc = s;
    #pragma unroll
    for (int off = 1; off < 64; off <<= 1) {
        int t = __shfl_up(inc, off, 64);
        if ((tid & 63) >= off) inc += t;
    }
    if ((tid & 63) == 63) wsum[tid >> 6] = inc;
    __syncthreads();
    int wpre = 0;
    #pragma unroll
    for (int wi = 0; wi < 4; ++wi) if (wi < (tid >> 6)) wpre += wsum[wi];
    int ex = wpre + inc - s;
    #pragma unroll
    for (int j = 0; j < 32; ++j) { rs[base + j] = ex; ex += v[j]; }
    if (tid == 0) rs[NN] = NE;
}

// scatter: 4 edges/thread; writes COMBINED edge record {src, w} as 8B int2
// (one store per edge instead of two random 4B stores -> half the sectors)
__global__ __launch_bounds__(256) void scatter_k(const int4* __restrict__ src4,
                                                 const int4* __restrict__ dst4,
                                                 const float4* __restrict__ w4,
                                                 const int* __restrict__ rs,
                                                 int* __restrict__ cursor,
                                                 int2* __restrict__ ep) {
    int i = blockIdx.x * 256 + threadIdx.x;   // grid = NE/4/256 = 256
    int4   s = src4[i];
    int4   d = dst4[i];
    float4 w = w4[i];
    int p;
    p = rs[d.x] + atomicAdd(&cursor[d.x], 1); ep[p] = make_int2(s.x, __float_as_int(w.x));
    p = rs[d.y] + atomicAdd(&cursor[d.y], 1); ep[p] = make_int2(s.y, __float_as_int(w.y));
    p = rs[d.z] + atomicAdd(&cursor[d.z], 1); ep[p] = make_int2(s.z, __float_as_int(w.z));
    p = rs[d.w] + atomicAdd(&cursor[d.w], 1); ep[p] = make_int2(s.w, __float_as_int(w.w));
}

// ---------------------------------------------------------------------------
// SPMM1 + relu, COLUMN-SPLIT x2 for per-XCD L2 residency:
// grid (1024, 2); y = column half (slowest dispatch dim -> temporal phases).
// Each phase gathers from a 4MB working set (128 cols of xw1) = one XCD L2.
// 8 rows/block, 32 lanes x float4 per row.
// ---------------------------------------------------------------------------
__global__ __launch_bounds__(256) void spmm1_k(const float* __restrict__ Hin,
                                               const int* __restrict__ rs,
                                               const int2* __restrict__ ep,
                                               float* __restrict__ H1) {
    const int tid = threadIdx.x;
    const int g   = tid >> 5;                         // row group 0..7
    const int lc  = blockIdx.y * 128 + (tid & 31) * 4; // col (float4)
    const int row = blockIdx.x * 8 + g;
    const int start = rs[row], end = rs[row + 1];
    float4 acc = make_float4(0.f, 0.f, 0.f, 0.f);
    for (int j = start; j < end; ++j) {
        int2 e = ep[j];
        const float w = __int_as_float(e.y);
        float4 v = *reinterpret_cast<const float4*>(&Hin[(size_t)e.x * D1 + lc]);
        acc.x += w * v.x; acc.y += w * v.y; acc.z += w * v.z; acc.w += w * v.w;
    }
    float4 r = make_float4(fmaxf(acc.x, 0.f), fmaxf(acc.y, 0.f),
                           fmaxf(acc.z, 0.f), fmaxf(acc.w, 0.f));
    *reinterpret_cast<float4*>(&H1[(size_t)row * D1 + lc]) = r;
}

// ---------------------------------------------------------------------------
// GEMM2: h1w2 = h1 @ W2 (4 rows/block, rows staged in LDS, W2 from L2)
// ---------------------------------------------------------------------------
__global__ __launch_bounds__(256) void gemm2_k(const float* __restrict__ H,
                                               const float* __restrict__ W,
                                               float* __restrict__ O) {
    __shared__ __align__(16) float hs[4][D1];
    const int tid = threadIdx.x;
    const int r = tid >> 6;
    const int c = tid & 63;
    const int row0 = blockIdx.x * 4;
    {
        int lr = tid >> 6, lc4 = tid & 63;
        *reinterpret_cast<float4*>(&hs[lr][lc4 * 4]) =
            *reinterpret_cast<const float4*>(&H[(size_t)(row0 + lr) * D1 + lc4 * 4]);
    }
    __syncthreads();
    float acc = 0.f;
    #pragma unroll 16
    for (int k = 0; k < D1; ++k) acc += hs[r][k] * W[k * D2 + c];
    O[(size_t)(row0 + r) * D2 + c] = acc;
}

// ---------------------------------------------------------------------------
// SPMM2 — float4 gather, 16 rows/block; h1w2 (2MB) is L2-resident.
// Emits z split into hi/lo bf16.
// ---------------------------------------------------------------------------
__global__ __launch_bounds__(256) void spmm64_k(const float* __restrict__ Hin,
                                                const int* __restrict__ rs,
                                                const int2* __restrict__ ep,
                                                __bf16* __restrict__ Zh,
                                                __bf16* __restrict__ Zl) {
    const int tid = threadIdx.x;
    const int g   = tid >> 4;          // row group 0..15
    const int lc  = (tid & 15) * 4;    // col (float4)
    const int row = blockIdx.x * 16 + g;
    const int start = rs[row], end = rs[row + 1];
    float4 acc = make_float4(0.f, 0.f, 0.f, 0.f);
    for (int j = start; j < end; ++j) {
        int2 e = ep[j];
        const float w = __int_as_float(e.y);
        float4 v = *reinterpret_cast<const float4*>(&Hin[(size_t)e.x * D2 + lc]);
        acc.x += w * v.x; acc.y += w * v.y; acc.z += w * v.z; acc.w += w * v.w;
    }
    float a[4] = {acc.x, acc.y, acc.z, acc.w};
    __bf16 h4[4], l4[4];
    #pragma unroll
    for (int e = 0; e < 4; ++e) {
        __bf16 h = (__bf16)a[e];
        h4[e] = h;
        l4[e] = (__bf16)(a[e] - (float)h);
    }
    *reinterpret_cast<uint2*>(&Zh[(size_t)row * D2 + lc]) = *reinterpret_cast<uint2*>(h4);
    *reinterpret_cast<uint2*>(&Zl[(size_t)row * D2 + lc]) = *reinterpret_cast<uint2*>(l4);
}

// ---------------------------------------------------------------------------
// ZZT via bf16 MFMA hi/lo split — R4/R10-proven form: full 4096-block grid,
// no LDS, NT scalar stores.
//   out = zh@zh^T + zh@zl^T + zl@zh^T
// ---------------------------------------------------------------------------
__global__ __launch_bounds__(256) void zzt_k(const __bf16* __restrict__ Zh,
                                             const __bf16* __restrict__ Zl,
                                             float* __restrict__ O) {
    const int tid  = threadIdx.x;
    const int lane = tid & 63;
    const int w    = tid >> 6;
    const int wm   = w >> 1;
    const int wn   = w & 1;
    const int r32  = lane & 31;
    const int kh   = lane >> 5;
    const int rowBase = blockIdx.y * 128 + wm * 64;
    const int colBase = blockIdx.x * 128 + wn * 64;

    f32x16 acc[2][2] = {};

    #pragma unroll
    for (int kk = 0; kk < 4; ++kk) {
        const int koff = kk * 16 + kh * 8;
        bf16x8 ah0 = *reinterpret_cast<const bf16x8*>(&Zh[(rowBase +      r32) * D2 + koff]);
        bf16x8 ah1 = *reinterpret_cast<const bf16x8*>(&Zh[(rowBase + 32 + r32) * D2 + koff]);
        bf16x8 al0 = *reinterpret_cast<const bf16x8*>(&Zl[(rowBase +      r32) * D2 + koff]);
        bf16x8 al1 = *reinterpret_cast<const bf16x8*>(&Zl[(rowBase + 32 + r32) * D2 + koff]);
        bf16x8 bh0 = *reinterpret_cast<const bf16x8*>(&Zh[(colBase +      r32) * D2 + koff]);
        bf16x8 bh1 = *reinterpret_cast<const bf16x8*>(&Zh[(colBase + 32 + r32) * D2 + koff]);
        bf16x8 bl0 = *reinterpret_cast<const bf16x8*>(&Zl[(colBase +      r32) * D2 + koff]);
        bf16x8 bl1 = *reinterpret_cast<const bf16x8*>(&Zl[(colBase + 32 + r32) * D2 + koff]);

        acc[0][0] = __builtin_amdgcn_mfma_f32_32x32x16_bf16(ah0, bh0, acc[0][0], 0, 0, 0);
        acc[0][1] = __builtin_amdgcn_mfma_f32_32x32x16_bf16(ah0, bh1, acc[0][1], 0, 0, 0);
        acc[1][0] = __builtin_amdgcn_mfma_f32_32x32x16_bf16(ah1, bh0, acc[1][0], 0, 0, 0);
        acc[1][1] = __builtin_amdgcn_mfma_f32_32x32x16_bf16(ah1, bh1, acc[1][1], 0, 0, 0);

        acc[0][0] = __builtin_amdgcn_mfma_f32_32x32x16_bf16(ah0, bl0, acc[0][0], 0, 0, 0);
        acc[0][1] = __builtin_amdgcn_mfma_f32_32x32x16_bf16(ah0, bl1, acc[0][1], 0, 0, 0);
        acc[1][0] = __builtin_amdgcn_mfma_f32_32x32x16_bf16(ah1, bl0, acc[1][0], 0, 0, 0);
        acc[1][1] = __builtin_amdgcn_mfma_f32_32x32x16_bf16(ah1, bl1, acc[1][1], 0, 0, 0);

        acc[0][0] = __builtin_amdgcn_mfma_f32_32x32x16_bf16(al0, bh0, acc[0][0], 0, 0, 0);
        acc[0][1] = __builtin_amdgcn_mfma_f32_32x32x16_bf16(al0, bh1, acc[0][1], 0, 0, 0);
        acc[1][0] = __builtin_amdgcn_mfma_f32_32x32x16_bf16(al1, bh0, acc[1][0], 0, 0, 0);
        acc[1][1] = __builtin_amdgcn_mfma_f32_32x32x16_bf16(al1, bh1, acc[1][1], 0, 0, 0);
    }

    #pragma unroll
    for (int i = 0; i < 2; ++i)
        #pragma unroll
        for (int j = 0; j < 2; ++j)
            #pragma unroll
            for (int reg = 0; reg < 16; ++reg) {
                int r = (reg & 3) + 8 * (reg >> 2) + 4 * kh;
                __builtin_nontemporal_store(acc[i][j][reg],
                    &O[(size_t)(rowBase + i * 32 + r) * NN + colBase + j * 32 + r32]);
            }
}

// ---------------------------------------------------------------------------
// Launch
// ---------------------------------------------------------------------------
extern "C" void kernel_launch(void* const* d_in, const int* in_sizes, int n_in,
                              void* d_out, int out_size, void* d_ws, size_t ws_size,
                              hipStream_t stream) {
    const float* x        = (const float*)d_in[0];
    const int*   edge_src = (const int*)d_in[1];
    const int*   edge_dst = (const int*)d_in[2];
    const float* edge_w   = (const float*)d_in[3];
    const float* W1       = (const float*)d_in[4];
    const float* W2       = (const float*)d_in[5];
    float* out = (float*)d_out;

    char* ws = (char*)d_ws;
    const size_t OFF_XW1  = 0;                                  // 8 MB
    const size_t OFF_H1   = OFF_XW1  + (size_t)NN * D1 * 4;     // 8 MB
    const size_t OFF_H1W2 = OFF_H1   + (size_t)NN * D1 * 4;     // 2 MB
    const size_t OFF_ZH   = OFF_H1W2 + (size_t)NN * D2 * 4;     // 1 MB
    const size_t OFF_ZL   = OFF_ZH   + (size_t)NN * D2 * 2;     // 1 MB
    const size_t OFF_WTH  = OFF_ZL   + (size_t)NN * D2 * 2;     // 256 KB
    const size_t OFF_WTL  = OFF_WTH  + (size_t)D0 * D1 * 2;     // 256 KB
    const size_t OFF_RS   = OFF_WTL  + (size_t)D0 * D1 * 2;     // (NN+1) ints
    const size_t OFF_CNT  = OFF_RS   + 33280;                   // NN ints (zeroed)
    const size_t OFF_CUR  = OFF_CNT  + (size_t)NN * 4;          // NN ints (zeroed)
    const size_t OFF_EP   = OFF_CUR  + (size_t)NN * 4;          // NE int2 (8B)

    float*  xw1  = (float*)(ws + OFF_XW1);
    float*  h1   = (float*)(ws + OFF_H1);
    float*  h1w2 = (float*)(ws + OFF_H1W2);
    __bf16* zh   = (__bf16*)(ws + OFF_ZH);
    __bf16* zl   = (__bf16*)(ws + OFF_ZL);
    __bf16* wth  = (__bf16*)(ws + OFF_WTH);
    __bf16* wtl  = (__bf16*)(ws + OFF_WTL);
    int*    rs   = (int*)(ws + OFF_RS);
    int*    cnt  = (int*)(ws + OFF_CNT);
    int*    cur  = (int*)(ws + OFF_CUR);
    int2*   ep   = (int2*)(ws + OFF_EP);

    // prep: zero(cnt+cur) + W1 -> W1T bf16 hi/lo
    prep_k<<<16 + 128, 256, 0, stream>>>(W1, (int4*)cnt, wth, wtl);

    // GEMM1 (512 blocks, 64x64 tiles) + edge_dst histogram (256 blocks)
    gemm1hist_k<<<512 + 256, 256, 0, stream>>>(x, wth, wtl, xw1,
                                               (const int4*)edge_dst, cnt);

    // CSR: scan + scatter (4 edges/thread, combined {src,w} records)
    scan_k<<<1, 256, 0, stream>>>(cnt, rs);
    scatter_k<<<NE / 4 / 256, 256, 0, stream>>>((const int4*)edge_src,
                                                (const int4*)edge_dst,
                                                (const float4*)edge_w,
                                                rs, cur, ep);

    // SPMM1 + relu (column-split x2: 4MB L2-resident gather per phase)
    spmm1_k<<<dim3(NN / 8, 2), 256, 0, stream>>>(xw1, rs, ep, h1);

    // GEMM2
    gemm2_k<<<NN / 4, 256, 0, stream>>>(h1, W2, h1w2);

    // SPMM2 -> zh/zl
    spmm64_k<<<NN / 16, 256, 0, stream>>>(h1w2, rs, ep, zh, zl);

    // recon = z @ z^T (full grid, NT direct stores)
    zzt_k<<<dim3(NN / 128, NN / 128), 256, 0, stream>>>(zh, zl, out);
}

// Round 13
// 209.950 us; speedup vs baseline: 1.0405x; 1.0405x over previous
//
#include <hip/hip_runtime.h>
#include <hip/hip_bf16.h>

// Problem constants
#define NN     8192      // nodes
#define D0     512       // x feature dim
#define D1     256       // hidden dim (W1 out)
#define D2     64        // z dim (W2 out)
#define NE     262144    // edges

typedef __attribute__((ext_vector_type(8)))  __bf16 bf16x8;
typedef __attribute__((ext_vector_type(16))) float  f32x16;

// ---------------------------------------------------------------------------
// prep_k: fused zero(cnt,cur) + convw1t (W1 -> W1T bf16 hi/lo)
// grid = 16 + 128 blocks
// ---------------------------------------------------------------------------
__global__ __launch_bounds__(256) void prep_k(const float* __restrict__ W,
                                              int4* __restrict__ zero_region,
                                              __bf16* __restrict__ Th,
                                              __bf16* __restrict__ Tl) {
    const int bid = blockIdx.x;
    const int tid = threadIdx.x;
    if (bid < 16) {
        zero_region[bid * 256 + tid] = make_int4(0, 0, 0, 0);
    } else {
        __shared__ float t[32][33];
        const int cid = bid - 16;
        const int c0 = (cid & 7) * 32;      // D1/32 = 8
        const int k0 = (cid >> 3) * 32;     // D0/32 = 16
        {
            int tr  = tid >> 3;
            int tc4 = tid & 7;
            float4 v = *reinterpret_cast<const float4*>(&W[(k0 + tr) * D1 + c0 + tc4 * 4]);
            t[tr][tc4 * 4 + 0] = v.x;
            t[tr][tc4 * 4 + 1] = v.y;
            t[tr][tc4 * 4 + 2] = v.z;
            t[tr][tc4 * 4 + 3] = v.w;
        }
        __syncthreads();
        int c  = tid >> 3;
        int kq = (tid & 7) * 4;
        __bf16 hv[4], lv[4];
        #pragma unroll
        for (int j = 0; j < 4; ++j) {
            float f = t[kq + j][c];
            hv[j] = (__bf16)f;
            lv[j] = (__bf16)(f - (float)hv[j]);
        }
        *reinterpret_cast<uint2*>(&Th[(size_t)(c0 + c) * D0 + k0 + kq]) = *reinterpret_cast<uint2*>(hv);
        *reinterpret_cast<uint2*>(&Tl[(size_t)(c0 + c) * D0 + k0 + kq]) = *reinterpret_cast<uint2*>(lv);
    }
}

// ---------------------------------------------------------------------------
// GEMM1 + hist fused.
// blocks [0,512): gemm1 64x64 tiles (4 waves 2x2, wave=32x32) — load-balances
//   across 256 CUs. blocks [512,768): edge_dst histogram.
// ---------------------------------------------------------------------------
__global__ __launch_bounds__(256) void gemm1hist_k(const float* __restrict__ X,
                                                   const __bf16* __restrict__ Wh,
                                                   const __bf16* __restrict__ Wl,
                                                   float* __restrict__ O,
                                                   const int4* __restrict__ dst4,
                                                   int* __restrict__ counts) {
    const int gid = blockIdx.x;
    const int tid = threadIdx.x;
    if (gid >= 512) {
        int i = (gid - 512) * 256 + tid;
        int4 d = dst4[i];
        atomicAdd(&counts[d.x], 1);
        atomicAdd(&counts[d.y], 1);
        atomicAdd(&counts[d.z], 1);
        atomicAdd(&counts[d.w], 1);
        return;
    }
    const int bx = gid >> 2;          // 0..127 row-block
    const int by = gid & 3;           // 0..3   col-block
    const int lane = tid & 63;
    const int w    = tid >> 6;
    const int wm   = w >> 1;
    const int wn   = w & 1;
    const int r32  = lane & 31;
    const int kh   = lane >> 5;
    const int row  = bx * 64 + wm * 32 + r32;
    const int col  = by * 64 + wn * 32 + r32;

    const float*  pX  = X  + (size_t)row * D0;
    const __bf16* pBh = Wh + (size_t)col * D0;
    const __bf16* pBl = Wl + (size_t)col * D0;

    f32x16 acc = {};
    #pragma unroll 4
    for (int k0 = 0; k0 < D0; k0 += 16) {
        const int koff = k0 + kh * 8;
        float4 f0 = *reinterpret_cast<const float4*>(pX + koff);
        float4 f1 = *reinterpret_cast<const float4*>(pX + koff + 4);
        float f[8] = {f0.x, f0.y, f0.z, f0.w, f1.x, f1.y, f1.z, f1.w};
        bf16x8 ah, al;
        #pragma unroll
        for (int e = 0; e < 8; ++e) {
            __bf16 hj = (__bf16)f[e];
            ah[e] = hj;
            al[e] = (__bf16)(f[e] - (float)hj);
        }
        bf16x8 bh = *reinterpret_cast<const bf16x8*>(pBh + koff);
        bf16x8 bl = *reinterpret_cast<const bf16x8*>(pBl + koff);
        acc = __builtin_amdgcn_mfma_f32_32x32x16_bf16(ah, bh, acc, 0, 0, 0);
        acc = __builtin_amdgcn_mfma_f32_32x32x16_bf16(ah, bl, acc, 0, 0, 0);
        acc = __builtin_amdgcn_mfma_f32_32x32x16_bf16(al, bh, acc, 0, 0, 0);
    }

    const int rowBase = bx * 64 + wm * 32;
    const int colBase = by * 64 + wn * 32;
    #pragma unroll
    for (int reg = 0; reg < 16; ++reg) {
        int r = (reg & 3) + 8 * (reg >> 2) + 4 * kh;
        O[(size_t)(rowBase + r) * D1 + colBase + r32] = acc[reg];
    }
}

// shuffle-based scan: 256 threads x 32 counts each
__global__ __launch_bounds__(256) void scan_k(const int* __restrict__ counts,
                                              int* __restrict__ rs) {
    __shared__ int wsum[4];
    const int tid  = threadIdx.x;
    const int base = tid * 32;
    int v[32];
    int s = 0;
    #pragma unroll
    for (int j = 0; j < 8; ++j) {
        int4 q = reinterpret_cast<const int4*>(&counts[base])[j];
        v[j * 4 + 0] = q.x; v[j * 4 + 1] = q.y; v[j * 4 + 2] = q.z; v[j * 4 + 3] = q.w;
        s += q.x + q.y + q.z + q.w;
    }
    int inc = s;
    #pragma unroll
    for (int off = 1; off < 64; off <<= 1) {
        int t = __shfl_up(inc, off, 64);
        if ((tid & 63) >= off) inc += t;
    }
    if ((tid & 63) == 63) wsum[tid >> 6] = inc;
    __syncthreads();
    int wpre = 0;
    #pragma unroll
    for (int wi = 0; wi < 4; ++wi) if (wi < (tid >> 6)) wpre += wsum[wi];
    int ex = wpre + inc - s;
    #pragma unroll
    for (int j = 0; j < 32; ++j) { rs[base + j] = ex; ex += v[j]; }
    if (tid == 0) rs[NN] = NE;
}

// scatter: 4 edges/thread; combined {src, w} 8B records
__global__ __launch_bounds__(256) void scatter_k(const int4* __restrict__ src4,
                                                 const int4* __restrict__ dst4,
                                                 const float4* __restrict__ w4,
                                                 const int* __restrict__ rs,
                                                 int* __restrict__ cursor,
                                                 int2* __restrict__ ep) {
    int i = blockIdx.x * 256 + threadIdx.x;   // grid = NE/4/256 = 256
    int4   s = src4[i];
    int4   d = dst4[i];
    float4 w = w4[i];
    int p;
    p = rs[d.x] + atomicAdd(&cursor[d.x], 1); ep[p] = make_int2(s.x, __float_as_int(w.x));
    p = rs[d.y] + atomicAdd(&cursor[d.y], 1); ep[p] = make_int2(s.y, __float_as_int(w.y));
    p = rs[d.z] + atomicAdd(&cursor[d.z], 1); ep[p] = make_int2(s.z, __float_as_int(w.z));
    p = rs[d.w] + atomicAdd(&cursor[d.w], 1); ep[p] = make_int2(s.w, __float_as_int(w.w));
}

// ---------------------------------------------------------------------------
// Fused SPMM1 + relu + GEMM2 (R11-proven structure) — float4 gather,
// 4 rows/block, 64 threads/row; gemm2 tail uses all 256 threads.
// ---------------------------------------------------------------------------
__global__ __launch_bounds__(256) void spmmfuse_k(const float* __restrict__ Hin,
                                                  const int* __restrict__ rs,
                                                  const int2* __restrict__ ep,
                                                  const float* __restrict__ W2,
                                                  float* __restrict__ H1W2) {
    __shared__ float h1row[4][D1];
    const int tid = threadIdx.x;
    const int g   = tid >> 6;          // row group 0..3
    const int lc  = (tid & 63) * 4;    // col (float4)
    const int row = blockIdx.x * 4 + g;
    const int start = rs[row], end = rs[row + 1];
    float4 acc = make_float4(0.f, 0.f, 0.f, 0.f);
    for (int j = start; j < end; ++j) {
        int2 e = ep[j];
        const float w = __int_as_float(e.y);
        float4 v = *reinterpret_cast<const float4*>(&Hin[(size_t)e.x * D1 + lc]);
        acc.x += w * v.x; acc.y += w * v.y; acc.z += w * v.z; acc.w += w * v.w;
    }
    h1row[g][lc + 0] = fmaxf(acc.x, 0.f);
    h1row[g][lc + 1] = fmaxf(acc.y, 0.f);
    h1row[g][lc + 2] = fmaxf(acc.z, 0.f);
    h1row[g][lc + 3] = fmaxf(acc.w, 0.f);
    __syncthreads();
    // gemm2: row = tid>>6, c = tid&63 (all 256 threads busy)
    const int c = tid & 63;
    float o = 0.f;
    #pragma unroll 16
    for (int k = 0; k < D1; ++k) o += h1row[g][k] * W2[k * D2 + c];
    H1W2[(size_t)row * D2 + c] = o;
}

// ---------------------------------------------------------------------------
// SPMM2 — float4 gather, 16 rows/block; h1w2 (2MB) is L2-resident.
// Emits z split into hi/lo bf16.
// ---------------------------------------------------------------------------
__global__ __launch_bounds__(256) void spmm64_k(const float* __restrict__ Hin,
                                                const int* __restrict__ rs,
                                                const int2* __restrict__ ep,
                                                __bf16* __restrict__ Zh,
                                                __bf16* __restrict__ Zl) {
    const int tid = threadIdx.x;
    const int g   = tid >> 4;          // row group 0..15
    const int lc  = (tid & 15) * 4;    // col (float4)
    const int row = blockIdx.x * 16 + g;
    const int start = rs[row], end = rs[row + 1];
    float4 acc = make_float4(0.f, 0.f, 0.f, 0.f);
    for (int j = start; j < end; ++j) {
        int2 e = ep[j];
        const float w = __int_as_float(e.y);
        float4 v = *reinterpret_cast<const float4*>(&Hin[(size_t)e.x * D2 + lc]);
        acc.x += w * v.x; acc.y += w * v.y; acc.z += w * v.z; acc.w += w * v.w;
    }
    float a[4] = {acc.x, acc.y, acc.z, acc.w};
    __bf16 h4[4], l4[4];
    #pragma unroll
    for (int e = 0; e < 4; ++e) {
        __bf16 h = (__bf16)a[e];
        h4[e] = h;
        l4[e] = (__bf16)(a[e] - (float)h);
    }
    *reinterpret_cast<uint2*>(&Zh[(size_t)row * D2 + lc]) = *reinterpret_cast<uint2*>(h4);
    *reinterpret_cast<uint2*>(&Zl[(size_t)row * D2 + lc]) = *reinterpret_cast<uint2*>(l4);
}

// ---------------------------------------------------------------------------
// ZZT via bf16 MFMA hi/lo split — R4/R10-proven form: full 4096-block grid,
// no LDS, NT scalar stores.
//   out = zh@zh^T + zh@zl^T + zl@zh^T
// ---------------------------------------------------------------------------
__global__ __launch_bounds__(256) void zzt_k(const __bf16* __restrict__ Zh,
                                             const __bf16* __restrict__ Zl,
                                             float* __restrict__ O) {
    const int tid  = threadIdx.x;
    const int lane = tid & 63;
    const int w    = tid >> 6;
    const int wm   = w >> 1;
    const int wn   = w & 1;
    const int r32  = lane & 31;
    const int kh   = lane >> 5;
    const int rowBase = blockIdx.y * 128 + wm * 64;
    const int colBase = blockIdx.x * 128 + wn * 64;

    f32x16 acc[2][2] = {};

    #pragma unroll
    for (int kk = 0; kk < 4; ++kk) {
        const int koff = kk * 16 + kh * 8;
        bf16x8 ah0 = *reinterpret_cast<const bf16x8*>(&Zh[(rowBase +      r32) * D2 + koff]);
        bf16x8 ah1 = *reinterpret_cast<const bf16x8*>(&Zh[(rowBase + 32 + r32) * D2 + koff]);
        bf16x8 al0 = *reinterpret_cast<const bf16x8*>(&Zl[(rowBase +      r32) * D2 + koff]);
        bf16x8 al1 = *reinterpret_cast<const bf16x8*>(&Zl[(rowBase + 32 + r32) * D2 + koff]);
        bf16x8 bh0 = *reinterpret_cast<const bf16x8*>(&Zh[(colBase +      r32) * D2 + koff]);
        bf16x8 bh1 = *reinterpret_cast<const bf16x8*>(&Zh[(colBase + 32 + r32) * D2 + koff]);
        bf16x8 bl0 = *reinterpret_cast<const bf16x8*>(&Zl[(colBase +      r32) * D2 + koff]);
        bf16x8 bl1 = *reinterpret_cast<const bf16x8*>(&Zl[(colBase + 32 + r32) * D2 + koff]);

        acc[0][0] = __builtin_amdgcn_mfma_f32_32x32x16_bf16(ah0, bh0, acc[0][0], 0, 0, 0);
        acc[0][1] = __builtin_amdgcn_mfma_f32_32x32x16_bf16(ah0, bh1, acc[0][1], 0, 0, 0);
        acc[1][0] = __builtin_amdgcn_mfma_f32_32x32x16_bf16(ah1, bh0, acc[1][0], 0, 0, 0);
        acc[1][1] = __builtin_amdgcn_mfma_f32_32x32x16_bf16(ah1, bh1, acc[1][1], 0, 0, 0);

        acc[0][0] = __builtin_amdgcn_mfma_f32_32x32x16_bf16(ah0, bl0, acc[0][0], 0, 0, 0);
        acc[0][1] = __builtin_amdgcn_mfma_f32_32x32x16_bf16(ah0, bl1, acc[0][1], 0, 0, 0);
        acc[1][0] = __builtin_amdgcn_mfma_f32_32x32x16_bf16(ah1, bl0, acc[1][0], 0, 0, 0);
        acc[1][1] = __builtin_amdgcn_mfma_f32_32x32x16_bf16(ah1, bl1, acc[1][1], 0, 0, 0);

        acc[0][0] = __builtin_amdgcn_mfma_f32_32x32x16_bf16(al0, bh0, acc[0][0], 0, 0, 0);
        acc[0][1] = __builtin_amdgcn_mfma_f32_32x32x16_bf16(al0, bh1, acc[0][1], 0, 0, 0);
        acc[1][0] = __builtin_amdgcn_mfma_f32_32x32x16_bf16(al1, bh0, acc[1][0], 0, 0, 0);
        acc[1][1] = __builtin_amdgcn_mfma_f32_32x32x16_bf16(al1, bh1, acc[1][1], 0, 0, 0);
    }

    #pragma unroll
    for (int i = 0; i < 2; ++i)
        #pragma unroll
        for (int j = 0; j < 2; ++j)
            #pragma unroll
            for (int reg = 0; reg < 16; ++reg) {
                int r = (reg & 3) + 8 * (reg >> 2) + 4 * kh;
                __builtin_nontemporal_store(acc[i][j][reg],
                    &O[(size_t)(rowBase + i * 32 + r) * NN + colBase + j * 32 + r32]);
            }
}

// ---------------------------------------------------------------------------
// Launch
// ---------------------------------------------------------------------------
extern "C" void kernel_launch(void* const* d_in, const int* in_sizes, int n_in,
                              void* d_out, int out_size, void* d_ws, size_t ws_size,
                              hipStream_t stream) {
    const float* x        = (const float*)d_in[0];
    const int*   edge_src = (const int*)d_in[1];
    const int*   edge_dst = (const int*)d_in[2];
    const float* edge_w   = (const float*)d_in[3];
    const float* W1       = (const float*)d_in[4];
    const float* W2       = (const float*)d_in[5];
    float* out = (float*)d_out;

    char* ws = (char*)d_ws;
    const size_t OFF_XW1  = 0;                                  // 8 MB
    const size_t OFF_H1W2 = OFF_XW1  + (size_t)NN * D1 * 4;     // 2 MB
    const size_t OFF_ZH   = OFF_H1W2 + (size_t)NN * D2 * 4;     // 1 MB
    const size_t OFF_ZL   = OFF_ZH   + (size_t)NN * D2 * 2;     // 1 MB
    const size_t OFF_WTH  = OFF_ZL   + (size_t)NN * D2 * 2;     // 256 KB
    const size_t OFF_WTL  = OFF_WTH  + (size_t)D0 * D1 * 2;     // 256 KB
    const size_t OFF_RS   = OFF_WTL  + (size_t)D0 * D1 * 2;     // (NN+1) ints
    const size_t OFF_CNT  = OFF_RS   + 33280;                   // NN ints (zeroed)
    const size_t OFF_CUR  = OFF_CNT  + (size_t)NN * 4;          // NN ints (zeroed)
    const size_t OFF_EP   = OFF_CUR  + (size_t)NN * 4;          // NE int2 (8B)

    float*  xw1  = (float*)(ws + OFF_XW1);
    float*  h1w2 = (float*)(ws + OFF_H1W2);
    __bf16* zh   = (__bf16*)(ws + OFF_ZH);
    __bf16* zl   = (__bf16*)(ws + OFF_ZL);
    __bf16* wth  = (__bf16*)(ws + OFF_WTH);
    __bf16* wtl  = (__bf16*)(ws + OFF_WTL);
    int*    rs   = (int*)(ws + OFF_RS);
    int*    cnt  = (int*)(ws + OFF_CNT);
    int*    cur  = (int*)(ws + OFF_CUR);
    int2*   ep   = (int2*)(ws + OFF_EP);

    // prep: zero(cnt+cur) + W1 -> W1T bf16 hi/lo
    prep_k<<<16 + 128, 256, 0, stream>>>(W1, (int4*)cnt, wth, wtl);

    // GEMM1 (512 blocks, 64x64 tiles) + edge_dst histogram (256 blocks)
    gemm1hist_k<<<512 + 256, 256, 0, stream>>>(x, wth, wtl, xw1,
                                               (const int4*)edge_dst, cnt);

    // CSR: scan + scatter (4 edges/thread, combined {src,w} records)
    scan_k<<<1, 256, 0, stream>>>(cnt, rs);
    scatter_k<<<NE / 4 / 256, 256, 0, stream>>>((const int4*)edge_src,
                                                (const int4*)edge_dst,
                                                (const float4*)edge_w,
                                                rs, cur, ep);

    // fused SPMM1 + relu + GEMM2 (float4 gather, 4 rows/block)
    spmmfuse_k<<<NN / 4, 256, 0, stream>>>(xw1, rs, ep, W2, h1w2);

    // SPMM2 -> zh/zl (float4 gather, 16 rows/block)
    spmm64_k<<<NN / 16, 256, 0, stream>>>(h1w2, rs, ep, zh, zl);

    // recon = z @ z^T (full grid, NT direct stores)
    zzt_k<<<dim3(NN / 128, NN / 128), 256, 0, stream>>>(zh, zl, out);
}

// Round 15
// 199.913 us; speedup vs baseline: 1.0927x; 1.0502x over previous
//
#include <hip/hip_runtime.h>
#include <hip/hip_bf16.h>

// Problem constants
#define NN     8192      // nodes
#define D0     512       // x feature dim
#define D1     256       // hidden dim (W1 out)
#define D2     64        // z dim (W2 out)
#define NE     262144    // edges

typedef __attribute__((ext_vector_type(8)))  __bf16   bf16x8;
typedef __attribute__((ext_vector_type(16))) float    f32x16;

// ---------------------------------------------------------------------------
// prep_k: fused zero(cnt,cur) + convw1t (W1 -> W1T bf16 hi/lo)
// grid = 16 + 128 blocks
// ---------------------------------------------------------------------------
__global__ __launch_bounds__(256) void prep_k(const float* __restrict__ W,
                                              int4* __restrict__ zero_region,
                                              __bf16* __restrict__ Th,
                                              __bf16* __restrict__ Tl) {
    const int bid = blockIdx.x;
    const int tid = threadIdx.x;
    if (bid < 16) {
        zero_region[bid * 256 + tid] = make_int4(0, 0, 0, 0);
    } else {
        __shared__ float t[32][33];
        const int cid = bid - 16;
        const int c0 = (cid & 7) * 32;      // D1/32 = 8
        const int k0 = (cid >> 3) * 32;     // D0/32 = 16
        {
            int tr  = tid >> 3;
            int tc4 = tid & 7;
            float4 v = *reinterpret_cast<const float4*>(&W[(k0 + tr) * D1 + c0 + tc4 * 4]);
            t[tr][tc4 * 4 + 0] = v.x;
            t[tr][tc4 * 4 + 1] = v.y;
            t[tr][tc4 * 4 + 2] = v.z;
            t[tr][tc4 * 4 + 3] = v.w;
        }
        __syncthreads();
        int c  = tid >> 3;
        int kq = (tid & 7) * 4;
        __bf16 hv[4], lv[4];
        #pragma unroll
        for (int j = 0; j < 4; ++j) {
            float f = t[kq + j][c];
            hv[j] = (__bf16)f;
            lv[j] = (__bf16)(f - (float)hv[j]);
        }
        *reinterpret_cast<uint2*>(&Th[(size_t)(c0 + c) * D0 + k0 + kq]) = *reinterpret_cast<uint2*>(hv);
        *reinterpret_cast<uint2*>(&Tl[(size_t)(c0 + c) * D0 + k0 + kq]) = *reinterpret_cast<uint2*>(lv);
    }
}

// ---------------------------------------------------------------------------
// GEMM1 + hist fused. xw1 stored fp32 (fp16 variant FAILED accuracy R14:
// deterministic quant error + replay-order noise exceeded the threshold).
// blocks [0,512): gemm1 64x64 tiles; [512,768): edge_dst histogram.
// ---------------------------------------------------------------------------
__global__ __launch_bounds__(256) void gemm1hist_k(const float* __restrict__ X,
                                                   const __bf16* __restrict__ Wh,
                                                   const __bf16* __restrict__ Wl,
                                                   float* __restrict__ O,
                                                   const int4* __restrict__ dst4,
                                                   int* __restrict__ counts) {
    const int gid = blockIdx.x;
    const int tid = threadIdx.x;
    if (gid >= 512) {
        int i = (gid - 512) * 256 + tid;
        int4 d = dst4[i];
        atomicAdd(&counts[d.x], 1);
        atomicAdd(&counts[d.y], 1);
        atomicAdd(&counts[d.z], 1);
        atomicAdd(&counts[d.w], 1);
        return;
    }
    const int bx = gid >> 2;          // 0..127 row-block
    const int by = gid & 3;           // 0..3   col-block
    const int lane = tid & 63;
    const int w    = tid >> 6;
    const int wm   = w >> 1;
    const int wn   = w & 1;
    const int r32  = lane & 31;
    const int kh   = lane >> 5;
    const int row  = bx * 64 + wm * 32 + r32;
    const int col  = by * 64 + wn * 32 + r32;

    const float*  pX  = X  + (size_t)row * D0;
    const __bf16* pBh = Wh + (size_t)col * D0;
    const __bf16* pBl = Wl + (size_t)col * D0;

    f32x16 acc = {};
    #pragma unroll 4
    for (int k0 = 0; k0 < D0; k0 += 16) {
        const int koff = k0 + kh * 8;
        float4 f0 = *reinterpret_cast<const float4*>(pX + koff);
        float4 f1 = *reinterpret_cast<const float4*>(pX + koff + 4);
        float f[8] = {f0.x, f0.y, f0.z, f0.w, f1.x, f1.y, f1.z, f1.w};
        bf16x8 ah, al;
        #pragma unroll
        for (int e = 0; e < 8; ++e) {
            __bf16 hj = (__bf16)f[e];
            ah[e] = hj;
            al[e] = (__bf16)(f[e] - (float)hj);
        }
        bf16x8 bh = *reinterpret_cast<const bf16x8*>(pBh + koff);
        bf16x8 bl = *reinterpret_cast<const bf16x8*>(pBl + koff);
        acc = __builtin_amdgcn_mfma_f32_32x32x16_bf16(ah, bh, acc, 0, 0, 0);
        acc = __builtin_amdgcn_mfma_f32_32x32x16_bf16(ah, bl, acc, 0, 0, 0);
        acc = __builtin_amdgcn_mfma_f32_32x32x16_bf16(al, bh, acc, 0, 0, 0);
    }

    const int rowBase = bx * 64 + wm * 32;
    const int colBase = by * 64 + wn * 32;
    #pragma unroll
    for (int reg = 0; reg < 16; ++reg) {
        int r = (reg & 3) + 8 * (reg >> 2) + 4 * kh;
        O[(size_t)(rowBase + r) * D1 + colBase + r32] = acc[reg];
    }
}

// shuffle-based scan: 256 threads x 32 counts each
__global__ __launch_bounds__(256) void scan_k(const int* __restrict__ counts,
                                              int* __restrict__ rs) {
    __shared__ int wsum[4];
    const int tid  = threadIdx.x;
    const int base = tid * 32;
    int v[32];
    int s = 0;
    #pragma unroll
    for (int j = 0; j < 8; ++j) {
        int4 q = reinterpret_cast<const int4*>(&counts[base])[j];
        v[j * 4 + 0] = q.x; v[j * 4 + 1] = q.y; v[j * 4 + 2] = q.z; v[j * 4 + 3] = q.w;
        s += q.x + q.y + q.z + q.w;
    }
    int inc = s;
    #pragma unroll
    for (int off = 1; off < 64; off <<= 1) {
        int t = __shfl_up(inc, off, 64);
        if ((tid & 63) >= off) inc += t;
    }
    if ((tid & 63) == 63) wsum[tid >> 6] = inc;
    __syncthreads();
    int wpre = 0;
    #pragma unroll
    for (int wi = 0; wi < 4; ++wi) if (wi < (tid >> 6)) wpre += wsum[wi];
    int ex = wpre + inc - s;
    #pragma unroll
    for (int j = 0; j < 32; ++j) { rs[base + j] = ex; ex += v[j]; }
    if (tid == 0) rs[NN] = NE;
}

// scatter: 4 edges/thread; combined {src, w} 8B records
__global__ __launch_bounds__(256) void scatter_k(const int4* __restrict__ src4,
                                                 const int4* __restrict__ dst4,
                                                 const float4* __restrict__ w4,
                                                 const int* __restrict__ rs,
                                                 int* __restrict__ cursor,
                                                 int2* __restrict__ ep) {
    int i = blockIdx.x * 256 + threadIdx.x;   // grid = NE/4/256 = 256
    int4   s = src4[i];
    int4   d = dst4[i];
    float4 w = w4[i];
    int p;
    p = rs[d.x] + atomicAdd(&cursor[d.x], 1); ep[p] = make_int2(s.x, __float_as_int(w.x));
    p = rs[d.y] + atomicAdd(&cursor[d.y], 1); ep[p] = make_int2(s.y, __float_as_int(w.y));
    p = rs[d.z] + atomicAdd(&cursor[d.z], 1); ep[p] = make_int2(s.z, __float_as_int(w.z));
    p = rs[d.w] + atomicAdd(&cursor[d.w], 1); ep[p] = make_int2(s.w, __float_as_int(w.w));
}

// ---------------------------------------------------------------------------
// Fused SPMM1 + relu + GEMM2 — fp32 float4 gather, 2-way j-unroll,
// 4 rows/block, 64 threads/row. GEMM2 tail uses all 256 threads.
// ---------------------------------------------------------------------------
__global__ __launch_bounds__(256) void spmmfuse_k(const float* __restrict__ Hin,
                                                  const int* __restrict__ rs,
                                                  const int2* __restrict__ ep,
                                                  const float* __restrict__ W2,
                                                  float* __restrict__ H1W2) {
    __shared__ float h1row[4][D1];
    const int tid = threadIdx.x;
    const int g   = tid >> 6;          // row group 0..3
    const int lc  = (tid & 63) * 4;    // col (float4)
    const int row = blockIdx.x * 4 + g;
    const int start = rs[row], end = rs[row + 1];
    float4 a0 = make_float4(0.f, 0.f, 0.f, 0.f);
    float4 a1 = make_float4(0.f, 0.f, 0.f, 0.f);
    int j = start;
    for (; j + 2 <= end; j += 2) {
        int2 e0 = ep[j];
        int2 e1 = ep[j + 1];
        float4 v0 = *reinterpret_cast<const float4*>(&Hin[(size_t)e0.x * D1 + lc]);
        float4 v1 = *reinterpret_cast<const float4*>(&Hin[(size_t)e1.x * D1 + lc]);
        const float w0 = __int_as_float(e0.y);
        const float w1 = __int_as_float(e1.y);
        a0.x += w0 * v0.x; a0.y += w0 * v0.y; a0.z += w0 * v0.z; a0.w += w0 * v0.w;
        a1.x += w1 * v1.x; a1.y += w1 * v1.y; a1.z += w1 * v1.z; a1.w += w1 * v1.w;
    }
    if (j < end) {
        int2 e0 = ep[j];
        float4 v0 = *reinterpret_cast<const float4*>(&Hin[(size_t)e0.x * D1 + lc]);
        const float w0 = __int_as_float(e0.y);
        a0.x += w0 * v0.x; a0.y += w0 * v0.y; a0.z += w0 * v0.z; a0.w += w0 * v0.w;
    }
    h1row[g][lc + 0] = fmaxf(a0.x + a1.x, 0.f);
    h1row[g][lc + 1] = fmaxf(a0.y + a1.y, 0.f);
    h1row[g][lc + 2] = fmaxf(a0.z + a1.z, 0.f);
    h1row[g][lc + 3] = fmaxf(a0.w + a1.w, 0.f);
    __syncthreads();
    // gemm2: row = tid>>6, c = tid&63 (all 256 threads busy)
    const int c = tid & 63;
    float o = 0.f;
    #pragma unroll 16
    for (int k = 0; k < D1; ++k) o += h1row[g][k] * W2[k * D2 + c];
    H1W2[(size_t)row * D2 + c] = o;
}

// ---------------------------------------------------------------------------
// SPMM2 — float4 gather with 2-way j-unroll, 16 rows/block; h1w2 (2MB)
// is L2-resident. Emits z split into hi/lo bf16.
// ---------------------------------------------------------------------------
__global__ __launch_bounds__(256) void spmm64_k(const float* __restrict__ Hin,
                                                const int* __restrict__ rs,
                                                const int2* __restrict__ ep,
                                                __bf16* __restrict__ Zh,
                                                __bf16* __restrict__ Zl) {
    const int tid = threadIdx.x;
    const int g   = tid >> 4;          // row group 0..15
    const int lc  = (tid & 15) * 4;    // col (float4)
    const int row = blockIdx.x * 16 + g;
    const int start = rs[row], end = rs[row + 1];
    float4 a0 = make_float4(0.f, 0.f, 0.f, 0.f);
    float4 a1 = make_float4(0.f, 0.f, 0.f, 0.f);
    int j = start;
    for (; j + 2 <= end; j += 2) {
        int2 e0 = ep[j];
        int2 e1 = ep[j + 1];
        float4 v0 = *reinterpret_cast<const float4*>(&Hin[(size_t)e0.x * D2 + lc]);
        float4 v1 = *reinterpret_cast<const float4*>(&Hin[(size_t)e1.x * D2 + lc]);
        const float w0 = __int_as_float(e0.y);
        const float w1 = __int_as_float(e1.y);
        a0.x += w0 * v0.x; a0.y += w0 * v0.y; a0.z += w0 * v0.z; a0.w += w0 * v0.w;
        a1.x += w1 * v1.x; a1.y += w1 * v1.y; a1.z += w1 * v1.z; a1.w += w1 * v1.w;
    }
    if (j < end) {
        int2 e0 = ep[j];
        float4 v0 = *reinterpret_cast<const float4*>(&Hin[(size_t)e0.x * D2 + lc]);
        const float w0 = __int_as_float(e0.y);
        a0.x += w0 * v0.x; a0.y += w0 * v0.y; a0.z += w0 * v0.z; a0.w += w0 * v0.w;
    }
    float a[4] = {a0.x + a1.x, a0.y + a1.y, a0.z + a1.z, a0.w + a1.w};
    __bf16 h4[4], l4[4];
    #pragma unroll
    for (int e = 0; e < 4; ++e) {
        __bf16 h = (__bf16)a[e];
        h4[e] = h;
        l4[e] = (__bf16)(a[e] - (float)h);
    }
    *reinterpret_cast<uint2*>(&Zh[(size_t)row * D2 + lc]) = *reinterpret_cast<uint2*>(h4);
    *reinterpret_cast<uint2*>(&Zl[(size_t)row * D2 + lc]) = *reinterpret_cast<uint2*>(l4);
}

// ---------------------------------------------------------------------------
// ZZT via bf16 MFMA hi/lo split — R4/R10-proven form: full 4096-block grid,
// no LDS, NT scalar stores.
//   out = zh@zh^T + zh@zl^T + zl@zh^T
// ---------------------------------------------------------------------------
__global__ __launch_bounds__(256) void zzt_k(const __bf16* __restrict__ Zh,
                                             const __bf16* __restrict__ Zl,
                                             float* __restrict__ O) {
    const int tid  = threadIdx.x;
    const int lane = tid & 63;
    const int w    = tid >> 6;
    const int wm   = w >> 1;
    const int wn   = w & 1;
    const int r32  = lane & 31;
    const int kh   = lane >> 5;
    const int rowBase = blockIdx.y * 128 + wm * 64;
    const int colBase = blockIdx.x * 128 + wn * 64;

    f32x16 acc[2][2] = {};

    #pragma unroll
    for (int kk = 0; kk < 4; ++kk) {
        const int koff = kk * 16 + kh * 8;
        bf16x8 ah0 = *reinterpret_cast<const bf16x8*>(&Zh[(rowBase +      r32) * D2 + koff]);
        bf16x8 ah1 = *reinterpret_cast<const bf16x8*>(&Zh[(rowBase + 32 + r32) * D2 + koff]);
        bf16x8 al0 = *reinterpret_cast<const bf16x8*>(&Zl[(rowBase +      r32) * D2 + koff]);
        bf16x8 al1 = *reinterpret_cast<const bf16x8*>(&Zl[(rowBase + 32 + r32) * D2 + koff]);
        bf16x8 bh0 = *reinterpret_cast<const bf16x8*>(&Zh[(colBase +      r32) * D2 + koff]);
        bf16x8 bh1 = *reinterpret_cast<const bf16x8*>(&Zh[(colBase + 32 + r32) * D2 + koff]);
        bf16x8 bl0 = *reinterpret_cast<const bf16x8*>(&Zl[(colBase +      r32) * D2 + koff]);
        bf16x8 bl1 = *reinterpret_cast<const bf16x8*>(&Zl[(colBase + 32 + r32) * D2 + koff]);

        acc[0][0] = __builtin_amdgcn_mfma_f32_32x32x16_bf16(ah0, bh0, acc[0][0], 0, 0, 0);
        acc[0][1] = __builtin_amdgcn_mfma_f32_32x32x16_bf16(ah0, bh1, acc[0][1], 0, 0, 0);
        acc[1][0] = __builtin_amdgcn_mfma_f32_32x32x16_bf16(ah1, bh0, acc[1][0], 0, 0, 0);
        acc[1][1] = __builtin_amdgcn_mfma_f32_32x32x16_bf16(ah1, bh1, acc[1][1], 0, 0, 0);

        acc[0][0] = __builtin_amdgcn_mfma_f32_32x32x16_bf16(ah0, bl0, acc[0][0], 0, 0, 0);
        acc[0][1] = __builtin_amdgcn_mfma_f32_32x32x16_bf16(ah0, bl1, acc[0][1], 0, 0, 0);
        acc[1][0] = __builtin_amdgcn_mfma_f32_32x32x16_bf16(ah1, bl0, acc[1][0], 0, 0, 0);
        acc[1][1] = __builtin_amdgcn_mfma_f32_32x32x16_bf16(ah1, bl1, acc[1][1], 0, 0, 0);

        acc[0][0] = __builtin_amdgcn_mfma_f32_32x32x16_bf16(al0, bh0, acc[0][0], 0, 0, 0);
        acc[0][1] = __builtin_amdgcn_mfma_f32_32x32x16_bf16(al0, bh1, acc[0][1], 0, 0, 0);
        acc[1][0] = __builtin_amdgcn_mfma_f32_32x32x16_bf16(al1, bh0, acc[1][0], 0, 0, 0);
        acc[1][1] = __builtin_amdgcn_mfma_f32_32x32x16_bf16(al1, bh1, acc[1][1], 0, 0, 0);
    }

    #pragma unroll
    for (int i = 0; i < 2; ++i)
        #pragma unroll
        for (int j = 0; j < 2; ++j)
            #pragma unroll
            for (int reg = 0; reg < 16; ++reg) {
                int r = (reg & 3) + 8 * (reg >> 2) + 4 * kh;
                __builtin_nontemporal_store(acc[i][j][reg],
                    &O[(size_t)(rowBase + i * 32 + r) * NN + colBase + j * 32 + r32]);
            }
}

// ---------------------------------------------------------------------------
// Launch
// ---------------------------------------------------------------------------
extern "C" void kernel_launch(void* const* d_in, const int* in_sizes, int n_in,
                              void* d_out, int out_size, void* d_ws, size_t ws_size,
                              hipStream_t stream) {
    const float* x        = (const float*)d_in[0];
    const int*   edge_src = (const int*)d_in[1];
    const int*   edge_dst = (const int*)d_in[2];
    const float* edge_w   = (const float*)d_in[3];
    const float* W1       = (const float*)d_in[4];
    const float* W2       = (const float*)d_in[5];
    float* out = (float*)d_out;

    char* ws = (char*)d_ws;
    const size_t OFF_XW1  = 0;                                  // 8 MB (fp32)
    const size_t OFF_H1W2 = OFF_XW1  + (size_t)NN * D1 * 4;     // 2 MB
    const size_t OFF_ZH   = OFF_H1W2 + (size_t)NN * D2 * 4;     // 1 MB
    const size_t OFF_ZL   = OFF_ZH   + (size_t)NN * D2 * 2;     // 1 MB
    const size_t OFF_WTH  = OFF_ZL   + (size_t)NN * D2 * 2;     // 256 KB
    const size_t OFF_WTL  = OFF_WTH  + (size_t)D0 * D1 * 2;     // 256 KB
    const size_t OFF_RS   = OFF_WTL  + (size_t)D0 * D1 * 2;     // (NN+1) ints
    const size_t OFF_CNT  = OFF_RS   + 33280;                   // NN ints (zeroed)
    const size_t OFF_CUR  = OFF_CNT  + (size_t)NN * 4;          // NN ints (zeroed)
    const size_t OFF_EP   = OFF_CUR  + (size_t)NN * 4;          // NE int2 (8B)

    float*  xw1  = (float*)(ws + OFF_XW1);
    float*  h1w2 = (float*)(ws + OFF_H1W2);
    __bf16* zh   = (__bf16*)(ws + OFF_ZH);
    __bf16* zl   = (__bf16*)(ws + OFF_ZL);
    __bf16* wth  = (__bf16*)(ws + OFF_WTH);
    __bf16* wtl  = (__bf16*)(ws + OFF_WTL);
    int*    rs   = (int*)(ws + OFF_RS);
    int*    cnt  = (int*)(ws + OFF_CNT);
    int*    cur  = (int*)(ws + OFF_CUR);
    int2*   ep   = (int2*)(ws + OFF_EP);

    // prep: zero(cnt+cur) + W1 -> W1T bf16 hi/lo
    prep_k<<<16 + 128, 256, 0, stream>>>(W1, (int4*)cnt, wth, wtl);

    // GEMM1 (512 blocks, 64x64 tiles) + edge_dst histogram (256 blocks)
    gemm1hist_k<<<512 + 256, 256, 0, stream>>>(x, wth, wtl, xw1,
                                               (const int4*)edge_dst, cnt);

    // CSR: scan + scatter (4 edges/thread, combined {src,w} records)
    scan_k<<<1, 256, 0, stream>>>(cnt, rs);
    scatter_k<<<NE / 4 / 256, 256, 0, stream>>>((const int4*)edge_src,
                                                (const int4*)edge_dst,
                                                (const float4*)edge_w,
                                                rs, cur, ep);

    // fused SPMM1 + relu + GEMM2 (fp32 float4 gather, 2-way unroll)
    spmmfuse_k<<<NN / 4, 256, 0, stream>>>(xw1, rs, ep, W2, h1w2);

    // SPMM2 -> zh/zl (float4 gather, 2-way unroll)
    spmm64_k<<<NN / 16, 256, 0, stream>>>(h1w2, rs, ep, zh, zl);

    // recon = z @ z^T (full grid, NT direct stores)
    zzt_k<<<dim3(NN / 128, NN / 128), 256, 0, stream>>>(zh, zl, out);
}

// Round 16
// 194.408 us; speedup vs baseline: 1.1236x; 1.0283x over previous
//
#include <hip/hip_runtime.h>
#include <hip/hip_bf16.h>

// Problem constants
#define NN     8192      // nodes
#define D0     512       // x feature dim
#define D1     256       // hidden dim (W1 out)
#define D2     64        // z dim (W2 out)
#define NE     262144    // edges

typedef __attribute__((ext_vector_type(8)))  __bf16   bf16x8;
typedef __attribute__((ext_vector_type(16))) float    f32x16;

// ---------------------------------------------------------------------------
// prep_k: fused zero(cnt,cur) + convw1t (W1 -> W1T bf16 hi/lo)
// grid = 16 + 128 blocks
// ---------------------------------------------------------------------------
__global__ __launch_bounds__(256) void prep_k(const float* __restrict__ W,
                                              int4* __restrict__ zero_region,
                                              __bf16* __restrict__ Th,
                                              __bf16* __restrict__ Tl) {
    const int bid = blockIdx.x;
    const int tid = threadIdx.x;
    if (bid < 16) {
        zero_region[bid * 256 + tid] = make_int4(0, 0, 0, 0);
    } else {
        __shared__ float t[32][33];
        const int cid = bid - 16;
        const int c0 = (cid & 7) * 32;      // D1/32 = 8
        const int k0 = (cid >> 3) * 32;     // D0/32 = 16
        {
            int tr  = tid >> 3;
            int tc4 = tid & 7;
            float4 v = *reinterpret_cast<const float4*>(&W[(k0 + tr) * D1 + c0 + tc4 * 4]);
            t[tr][tc4 * 4 + 0] = v.x;
            t[tr][tc4 * 4 + 1] = v.y;
            t[tr][tc4 * 4 + 2] = v.z;
            t[tr][tc4 * 4 + 3] = v.w;
        }
        __syncthreads();
        int c  = tid >> 3;
        int kq = (tid & 7) * 4;
        __bf16 hv[4], lv[4];
        #pragma unroll
        for (int j = 0; j < 4; ++j) {
            float f = t[kq + j][c];
            hv[j] = (__bf16)f;
            lv[j] = (__bf16)(f - (float)hv[j]);
        }
        *reinterpret_cast<uint2*>(&Th[(size_t)(c0 + c) * D0 + k0 + kq]) = *reinterpret_cast<uint2*>(hv);
        *reinterpret_cast<uint2*>(&Tl[(size_t)(c0 + c) * D0 + k0 + kq]) = *reinterpret_cast<uint2*>(lv);
    }
}

// ---------------------------------------------------------------------------
// GEMM1 + hist fused. xw1 stored fp32 (fp16 variant FAILED accuracy R14).
// blocks [0,512): gemm1 64x64 tiles; [512,768): edge_dst histogram.
// ---------------------------------------------------------------------------
__global__ __launch_bounds__(256) void gemm1hist_k(const float* __restrict__ X,
                                                   const __bf16* __restrict__ Wh,
                                                   const __bf16* __restrict__ Wl,
                                                   float* __restrict__ O,
                                                   const int4* __restrict__ dst4,
                                                   int* __restrict__ counts) {
    const int gid = blockIdx.x;
    const int tid = threadIdx.x;
    if (gid >= 512) {
        int i = (gid - 512) * 256 + tid;
        int4 d = dst4[i];
        atomicAdd(&counts[d.x], 1);
        atomicAdd(&counts[d.y], 1);
        atomicAdd(&counts[d.z], 1);
        atomicAdd(&counts[d.w], 1);
        return;
    }
    const int bx = gid >> 2;          // 0..127 row-block
    const int by = gid & 3;           // 0..3   col-block
    const int lane = tid & 63;
    const int w    = tid >> 6;
    const int wm   = w >> 1;
    const int wn   = w & 1;
    const int r32  = lane & 31;
    const int kh   = lane >> 5;
    const int row  = bx * 64 + wm * 32 + r32;
    const int col  = by * 64 + wn * 32 + r32;

    const float*  pX  = X  + (size_t)row * D0;
    const __bf16* pBh = Wh + (size_t)col * D0;
    const __bf16* pBl = Wl + (size_t)col * D0;

    f32x16 acc = {};
    #pragma unroll 4
    for (int k0 = 0; k0 < D0; k0 += 16) {
        const int koff = k0 + kh * 8;
        float4 f0 = *reinterpret_cast<const float4*>(pX + koff);
        float4 f1 = *reinterpret_cast<const float4*>(pX + koff + 4);
        float f[8] = {f0.x, f0.y, f0.z, f0.w, f1.x, f1.y, f1.z, f1.w};
        bf16x8 ah, al;
        #pragma unroll
        for (int e = 0; e < 8; ++e) {
            __bf16 hj = (__bf16)f[e];
            ah[e] = hj;
            al[e] = (__bf16)(f[e] - (float)hj);
        }
        bf16x8 bh = *reinterpret_cast<const bf16x8*>(pBh + koff);
        bf16x8 bl = *reinterpret_cast<const bf16x8*>(pBl + koff);
        acc = __builtin_amdgcn_mfma_f32_32x32x16_bf16(ah, bh, acc, 0, 0, 0);
        acc = __builtin_amdgcn_mfma_f32_32x32x16_bf16(ah, bl, acc, 0, 0, 0);
        acc = __builtin_amdgcn_mfma_f32_32x32x16_bf16(al, bh, acc, 0, 0, 0);
    }

    const int rowBase = bx * 64 + wm * 32;
    const int colBase = by * 64 + wn * 32;
    #pragma unroll
    for (int reg = 0; reg < 16; ++reg) {
        int r = (reg & 3) + 8 * (reg >> 2) + 4 * kh;
        O[(size_t)(rowBase + r) * D1 + colBase + r32] = acc[reg];
    }
}

// shuffle-based scan: 256 threads x 32 counts each
__global__ __launch_bounds__(256) void scan_k(const int* __restrict__ counts,
                                              int* __restrict__ rs) {
    __shared__ int wsum[4];
    const int tid  = threadIdx.x;
    const int base = tid * 32;
    int v[32];
    int s = 0;
    #pragma unroll
    for (int j = 0; j < 8; ++j) {
        int4 q = reinterpret_cast<const int4*>(&counts[base])[j];
        v[j * 4 + 0] = q.x; v[j * 4 + 1] = q.y; v[j * 4 + 2] = q.z; v[j * 4 + 3] = q.w;
        s += q.x + q.y + q.z + q.w;
    }
    int inc = s;
    #pragma unroll
    for (int off = 1; off < 64; off <<= 1) {
        int t = __shfl_up(inc, off, 64);
        if ((tid & 63) >= off) inc += t;
    }
    if ((tid & 63) == 63) wsum[tid >> 6] = inc;
    __syncthreads();
    int wpre = 0;
    #pragma unroll
    for (int wi = 0; wi < 4; ++wi) if (wi < (tid >> 6)) wpre += wsum[wi];
    int ex = wpre + inc - s;
    #pragma unroll
    for (int j = 0; j < 32; ++j) { rs[base + j] = ex; ex += v[j]; }
    if (tid == 0) rs[NN] = NE;
}

// scatter: 4 edges/thread; combined {src, w} 8B records
__global__ __launch_bounds__(256) void scatter_k(const int4* __restrict__ src4,
                                                 const int4* __restrict__ dst4,
                                                 const float4* __restrict__ w4,
                                                 const int* __restrict__ rs,
                                                 int* __restrict__ cursor,
                                                 int2* __restrict__ ep) {
    int i = blockIdx.x * 256 + threadIdx.x;   // grid = NE/4/256 = 256
    int4   s = src4[i];
    int4   d = dst4[i];
    float4 w = w4[i];
    int p;
    p = rs[d.x] + atomicAdd(&cursor[d.x], 1); ep[p] = make_int2(s.x, __float_as_int(w.x));
    p = rs[d.y] + atomicAdd(&cursor[d.y], 1); ep[p] = make_int2(s.y, __float_as_int(w.y));
    p = rs[d.z] + atomicAdd(&cursor[d.z], 1); ep[p] = make_int2(s.z, __float_as_int(w.z));
    p = rs[d.w] + atomicAdd(&cursor[d.w], 1); ep[p] = make_int2(s.w, __float_as_int(w.w));
}

// ---------------------------------------------------------------------------
// Fused SPMM1 + relu + GEMM2 — fp32 float4 gather, 4-way j-unroll
// (4 outstanding gathers/lane), 4 rows/block, 64 threads/row.
// GEMM2 tail uses all 256 threads.
// ---------------------------------------------------------------------------
__global__ __launch_bounds__(256) void spmmfuse_k(const float* __restrict__ Hin,
                                                  const int* __restrict__ rs,
                                                  const int2* __restrict__ ep,
                                                  const float* __restrict__ W2,
                                                  float* __restrict__ H1W2) {
    __shared__ float h1row[4][D1];
    const int tid = threadIdx.x;
    const int g   = tid >> 6;          // row group 0..3
    const int lc  = (tid & 63) * 4;    // col (float4)
    const int row = blockIdx.x * 4 + g;
    const int start = rs[row], end = rs[row + 1];
    float4 a0 = make_float4(0.f, 0.f, 0.f, 0.f);
    float4 a1 = make_float4(0.f, 0.f, 0.f, 0.f);
    float4 a2 = make_float4(0.f, 0.f, 0.f, 0.f);
    float4 a3 = make_float4(0.f, 0.f, 0.f, 0.f);
    int j = start;
    for (; j + 4 <= end; j += 4) {
        int2 e0 = ep[j];
        int2 e1 = ep[j + 1];
        int2 e2 = ep[j + 2];
        int2 e3 = ep[j + 3];
        float4 v0 = *reinterpret_cast<const float4*>(&Hin[(size_t)e0.x * D1 + lc]);
        float4 v1 = *reinterpret_cast<const float4*>(&Hin[(size_t)e1.x * D1 + lc]);
        float4 v2 = *reinterpret_cast<const float4*>(&Hin[(size_t)e2.x * D1 + lc]);
        float4 v3 = *reinterpret_cast<const float4*>(&Hin[(size_t)e3.x * D1 + lc]);
        const float w0 = __int_as_float(e0.y);
        const float w1 = __int_as_float(e1.y);
        const float w2 = __int_as_float(e2.y);
        const float w3 = __int_as_float(e3.y);
        a0.x += w0 * v0.x; a0.y += w0 * v0.y; a0.z += w0 * v0.z; a0.w += w0 * v0.w;
        a1.x += w1 * v1.x; a1.y += w1 * v1.y; a1.z += w1 * v1.z; a1.w += w1 * v1.w;
        a2.x += w2 * v2.x; a2.y += w2 * v2.y; a2.z += w2 * v2.z; a2.w += w2 * v2.w;
        a3.x += w3 * v3.x; a3.y += w3 * v3.y; a3.z += w3 * v3.z; a3.w += w3 * v3.w;
    }
    for (; j < end; ++j) {
        int2 e0 = ep[j];
        float4 v0 = *reinterpret_cast<const float4*>(&Hin[(size_t)e0.x * D1 + lc]);
        const float w0 = __int_as_float(e0.y);
        a0.x += w0 * v0.x; a0.y += w0 * v0.y; a0.z += w0 * v0.z; a0.w += w0 * v0.w;
    }
    h1row[g][lc + 0] = fmaxf(a0.x + a1.x + a2.x + a3.x, 0.f);
    h1row[g][lc + 1] = fmaxf(a0.y + a1.y + a2.y + a3.y, 0.f);
    h1row[g][lc + 2] = fmaxf(a0.z + a1.z + a2.z + a3.z, 0.f);
    h1row[g][lc + 3] = fmaxf(a0.w + a1.w + a2.w + a3.w, 0.f);
    __syncthreads();
    // gemm2: row = tid>>6, c = tid&63 (all 256 threads busy)
    const int c = tid & 63;
    float o = 0.f;
    #pragma unroll 16
    for (int k = 0; k < D1; ++k) o += h1row[g][k] * W2[k * D2 + c];
    H1W2[(size_t)row * D2 + c] = o;
}

// ---------------------------------------------------------------------------
// SPMM2 — float4 gather with 4-way j-unroll, 16 rows/block; h1w2 (2MB)
// is L2-resident. Emits z split into hi/lo bf16.
// ---------------------------------------------------------------------------
__global__ __launch_bounds__(256) void spmm64_k(const float* __restrict__ Hin,
                                                const int* __restrict__ rs,
                                                const int2* __restrict__ ep,
                                                __bf16* __restrict__ Zh,
                                                __bf16* __restrict__ Zl) {
    const int tid = threadIdx.x;
    const int g   = tid >> 4;          // row group 0..15
    const int lc  = (tid & 15) * 4;    // col (float4)
    const int row = blockIdx.x * 16 + g;
    const int start = rs[row], end = rs[row + 1];
    float4 a0 = make_float4(0.f, 0.f, 0.f, 0.f);
    float4 a1 = make_float4(0.f, 0.f, 0.f, 0.f);
    float4 a2 = make_float4(0.f, 0.f, 0.f, 0.f);
    float4 a3 = make_float4(0.f, 0.f, 0.f, 0.f);
    int j = start;
    for (; j + 4 <= end; j += 4) {
        int2 e0 = ep[j];
        int2 e1 = ep[j + 1];
        int2 e2 = ep[j + 2];
        int2 e3 = ep[j + 3];
        float4 v0 = *reinterpret_cast<const float4*>(&Hin[(size_t)e0.x * D2 + lc]);
        float4 v1 = *reinterpret_cast<const float4*>(&Hin[(size_t)e1.x * D2 + lc]);
        float4 v2 = *reinterpret_cast<const float4*>(&Hin[(size_t)e2.x * D2 + lc]);
        float4 v3 = *reinterpret_cast<const float4*>(&Hin[(size_t)e3.x * D2 + lc]);
        const float w0 = __int_as_float(e0.y);
        const float w1 = __int_as_float(e1.y);
        const float w2 = __int_as_float(e2.y);
        const float w3 = __int_as_float(e3.y);
        a0.x += w0 * v0.x; a0.y += w0 * v0.y; a0.z += w0 * v0.z; a0.w += w0 * v0.w;
        a1.x += w1 * v1.x; a1.y += w1 * v1.y; a1.z += w1 * v1.z; a1.w += w1 * v1.w;
        a2.x += w2 * v2.x; a2.y += w2 * v2.y; a2.z += w2 * v2.z; a2.w += w2 * v2.w;
        a3.x += w3 * v3.x; a3.y += w3 * v3.y; a3.z += w3 * v3.z; a3.w += w3 * v3.w;
    }
    for (; j < end; ++j) {
        int2 e0 = ep[j];
        float4 v0 = *reinterpret_cast<const float4*>(&Hin[(size_t)e0.x * D2 + lc]);
        const float w0 = __int_as_float(e0.y);
        a0.x += w0 * v0.x; a0.y += w0 * v0.y; a0.z += w0 * v0.z; a0.w += w0 * v0.w;
    }
    float a[4] = {a0.x + a1.x + a2.x + a3.x, a0.y + a1.y + a2.y + a3.y,
                  a0.z + a1.z + a2.z + a3.z, a0.w + a1.w + a2.w + a3.w};
    __bf16 h4[4], l4[4];
    #pragma unroll
    for (int e = 0; e < 4; ++e) {
        __bf16 h = (__bf16)a[e];
        h4[e] = h;
        l4[e] = (__bf16)(a[e] - (float)h);
    }
    *reinterpret_cast<uint2*>(&Zh[(size_t)row * D2 + lc]) = *reinterpret_cast<uint2*>(h4);
    *reinterpret_cast<uint2*>(&Zl[(size_t)row * D2 + lc]) = *reinterpret_cast<uint2*>(l4);
}

// ---------------------------------------------------------------------------
// ZZT via bf16 MFMA hi/lo split — R4/R10-proven form: full 4096-block grid,
// no LDS, NT scalar stores.
//   out = zh@zh^T + zh@zl^T + zl@zh^T
// ---------------------------------------------------------------------------
__global__ __launch_bounds__(256) void zzt_k(const __bf16* __restrict__ Zh,
                                             const __bf16* __restrict__ Zl,
                                             float* __restrict__ O) {
    const int tid  = threadIdx.x;
    const int lane = tid & 63;
    const int w    = tid >> 6;
    const int wm   = w >> 1;
    const int wn   = w & 1;
    const int r32  = lane & 31;
    const int kh   = lane >> 5;
    const int rowBase = blockIdx.y * 128 + wm * 64;
    const int colBase = blockIdx.x * 128 + wn * 64;

    f32x16 acc[2][2] = {};

    #pragma unroll
    for (int kk = 0; kk < 4; ++kk) {
        const int koff = kk * 16 + kh * 8;
        bf16x8 ah0 = *reinterpret_cast<const bf16x8*>(&Zh[(rowBase +      r32) * D2 + koff]);
        bf16x8 ah1 = *reinterpret_cast<const bf16x8*>(&Zh[(rowBase + 32 + r32) * D2 + koff]);
        bf16x8 al0 = *reinterpret_cast<const bf16x8*>(&Zl[(rowBase +      r32) * D2 + koff]);
        bf16x8 al1 = *reinterpret_cast<const bf16x8*>(&Zl[(rowBase + 32 + r32) * D2 + koff]);
        bf16x8 bh0 = *reinterpret_cast<const bf16x8*>(&Zh[(colBase +      r32) * D2 + koff]);
        bf16x8 bh1 = *reinterpret_cast<const bf16x8*>(&Zh[(colBase + 32 + r32) * D2 + koff]);
        bf16x8 bl0 = *reinterpret_cast<const bf16x8*>(&Zl[(colBase +      r32) * D2 + koff]);
        bf16x8 bl1 = *reinterpret_cast<const bf16x8*>(&Zl[(colBase + 32 + r32) * D2 + koff]);

        acc[0][0] = __builtin_amdgcn_mfma_f32_32x32x16_bf16(ah0, bh0, acc[0][0], 0, 0, 0);
        acc[0][1] = __builtin_amdgcn_mfma_f32_32x32x16_bf16(ah0, bh1, acc[0][1], 0, 0, 0);
        acc[1][0] = __builtin_amdgcn_mfma_f32_32x32x16_bf16(ah1, bh0, acc[1][0], 0, 0, 0);
        acc[1][1] = __builtin_amdgcn_mfma_f32_32x32x16_bf16(ah1, bh1, acc[1][1], 0, 0, 0);

        acc[0][0] = __builtin_amdgcn_mfma_f32_32x32x16_bf16(ah0, bl0, acc[0][0], 0, 0, 0);
        acc[0][1] = __builtin_amdgcn_mfma_f32_32x32x16_bf16(ah0, bl1, acc[0][1], 0, 0, 0);
        acc[1][0] = __builtin_amdgcn_mfma_f32_32x32x16_bf16(ah1, bl0, acc[1][0], 0, 0, 0);
        acc[1][1] = __builtin_amdgcn_mfma_f32_32x32x16_bf16(ah1, bl1, acc[1][1], 0, 0, 0);

        acc[0][0] = __builtin_amdgcn_mfma_f32_32x32x16_bf16(al0, bh0, acc[0][0], 0, 0, 0);
        acc[0][1] = __builtin_amdgcn_mfma_f32_32x32x16_bf16(al0, bh1, acc[0][1], 0, 0, 0);
        acc[1][0] = __builtin_amdgcn_mfma_f32_32x32x16_bf16(al1, bh0, acc[1][0], 0, 0, 0);
        acc[1][1] = __builtin_amdgcn_mfma_f32_32x32x16_bf16(al1, bh1, acc[1][1], 0, 0, 0);
    }

    #pragma unroll
    for (int i = 0; i < 2; ++i)
        #pragma unroll
        for (int j = 0; j < 2; ++j)
            #pragma unroll
            for (int reg = 0; reg < 16; ++reg) {
                int r = (reg & 3) + 8 * (reg >> 2) + 4 * kh;
                __builtin_nontemporal_store(acc[i][j][reg],
                    &O[(size_t)(rowBase + i * 32 + r) * NN + colBase + j * 32 + r32]);
            }
}

// ---------------------------------------------------------------------------
// Launch
// ---------------------------------------------------------------------------
extern "C" void kernel_launch(void* const* d_in, const int* in_sizes, int n_in,
                              void* d_out, int out_size, void* d_ws, size_t ws_size,
                              hipStream_t stream) {
    const float* x        = (const float*)d_in[0];
    const int*   edge_src = (const int*)d_in[1];
    const int*   edge_dst = (const int*)d_in[2];
    const float* edge_w   = (const float*)d_in[3];
    const float* W1       = (const float*)d_in[4];
    const float* W2       = (const float*)d_in[5];
    float* out = (float*)d_out;

    char* ws = (char*)d_ws;
    const size_t OFF_XW1  = 0;                                  // 8 MB (fp32)
    const size_t OFF_H1W2 = OFF_XW1  + (size_t)NN * D1 * 4;     // 2 MB
    const size_t OFF_ZH   = OFF_H1W2 + (size_t)NN * D2 * 4;     // 1 MB
    const size_t OFF_ZL   = OFF_ZH   + (size_t)NN * D2 * 2;     // 1 MB
    const size_t OFF_WTH  = OFF_ZL   + (size_t)NN * D2 * 2;     // 256 KB
    const size_t OFF_WTL  = OFF_WTH  + (size_t)D0 * D1 * 2;     // 256 KB
    const size_t OFF_RS   = OFF_WTL  + (size_t)D0 * D1 * 2;     // (NN+1) ints
    const size_t OFF_CNT  = OFF_RS   + 33280;                   // NN ints (zeroed)
    const size_t OFF_CUR  = OFF_CNT  + (size_t)NN * 4;          // NN ints (zeroed)
    const size_t OFF_EP   = OFF_CUR  + (size_t)NN * 4;          // NE int2 (8B)

    float*  xw1  = (float*)(ws + OFF_XW1);
    float*  h1w2 = (float*)(ws + OFF_H1W2);
    __bf16* zh   = (__bf16*)(ws + OFF_ZH);
    __bf16* zl   = (__bf16*)(ws + OFF_ZL);
    __bf16* wth  = (__bf16*)(ws + OFF_WTH);
    __bf16* wtl  = (__bf16*)(ws + OFF_WTL);
    int*    rs   = (int*)(ws + OFF_RS);
    int*    cnt  = (int*)(ws + OFF_CNT);
    int*    cur  = (int*)(ws + OFF_CUR);
    int2*   ep   = (int2*)(ws + OFF_EP);

    // prep: zero(cnt+cur) + W1 -> W1T bf16 hi/lo
    prep_k<<<16 + 128, 256, 0, stream>>>(W1, (int4*)cnt, wth, wtl);

    // GEMM1 (512 blocks, 64x64 tiles) + edge_dst histogram (256 blocks)
    gemm1hist_k<<<512 + 256, 256, 0, stream>>>(x, wth, wtl, xw1,
                                               (const int4*)edge_dst, cnt);

    // CSR: scan + scatter (4 edges/thread, combined {src,w} records)
    scan_k<<<1, 256, 0, stream>>>(cnt, rs);
    scatter_k<<<NE / 4 / 256, 256, 0, stream>>>((const int4*)edge_src,
                                                (const int4*)edge_dst,
                                                (const float4*)edge_w,
                                                rs, cur, ep);

    // fused SPMM1 + relu + GEMM2 (fp32 float4 gather, 4-way unroll)
    spmmfuse_k<<<NN / 4, 256, 0, stream>>>(xw1, rs, ep, W2, h1w2);

    // SPMM2 -> zh/zl (float4 gather, 4-way unroll)
    spmm64_k<<<NN / 16, 256, 0, stream>>>(h1w2, rs, ep, zh, zl);

    // recon = z @ z^T (full grid, NT direct stores)
    zzt_k<<<dim3(NN / 128, NN / 128), 256, 0, stream>>>(zh, zl, out);
}